// Round 1
// baseline (2688.982 us; speedup 1.0000x reference)
//
#include <hip/hip_runtime.h>

// MyRNNCell: x (B,T,D) fp32, h0 (B,U) fp32, W (D+U, U) fp32, bias (U) fp32.
//   Wh = W[:U]  (U x U),  Wx = W[U:]  (D x U)
//   xp[b,t,u] = sum_d x[b,t,d] * Wx[d,u] + bias[u]
//   h_{t+1}[b,u] = tanh( sum_j h_t[b,j]*Wh[j,u] + xp[b,t,u] );  out[b,t,:] = h_{t+1}
//
// Mapping: one workgroup per batch element (256 wgs = 256 CUs), 256 threads,
// thread u owns output unit u and holds W column u (384 fp32) in VGPRs.
// h double-buffered in LDS (broadcast reads are conflict-free); next x row
// prefetched into regs each step. One barrier per step. No global sync ever.

constexpr int B = 256;
constexpr int T = 1024;
constexpr int D = 128;
constexpr int U = 256;

__global__ __launch_bounds__(256, 1)
void rnn_fused_kernel(const float* __restrict__ x,
                      const float* __restrict__ h0,
                      const float* __restrict__ W,
                      const float* __restrict__ bias,
                      float* __restrict__ out) {
    const int b = blockIdx.x;
    const int u = threadIdx.x;   // 0..255, one output unit per thread

    __shared__ float hbuf[2][U];   // double-buffered hidden state
    __shared__ float xb[2][D];     // double-buffered x_t row

    // Load W column u into registers: wcol[j] = W[j][u].
    // j in [0,U): Wh rows; j in [U, U+D): Wx rows.
    float wcol[U + D];
#pragma unroll
    for (int j = 0; j < U + D; ++j) {
        wcol[j] = W[(size_t)j * U + u];
    }

    const float bu = bias[u];

    // Init h and stage x_0.
    hbuf[0][u] = h0[(size_t)b * U + u];
    if (u < D) xb[0][u] = x[((size_t)b * T) * D + u];
    __syncthreads();

    const float* xrow = x + (size_t)b * T * D;
    float*       orow = out + (size_t)b * T * U;

    for (int t = 0; t < T; ++t) {
        const int cur = t & 1;
        const int nxt = cur ^ 1;

        // Prefetch next x row (latency hides under the FMA body below).
        float xn = 0.0f;
        if (u < D && t + 1 < T) xn = xrow[(size_t)(t + 1) * D + u];

        // 4 independent accumulator chains (fma latency 4cyc, tput 2cyc).
        float a0 = bu, a1 = 0.0f, a2 = 0.0f, a3 = 0.0f;

        // x_proj part: sum_d xb[d] * Wx[d][u]
#pragma unroll
        for (int d = 0; d < D; d += 4) {
            const float4 x4 = *reinterpret_cast<const float4*>(&xb[cur][d]);
            a0 += x4.x * wcol[U + d + 0];
            a1 += x4.y * wcol[U + d + 1];
            a2 += x4.z * wcol[U + d + 2];
            a3 += x4.w * wcol[U + d + 3];
        }
        // recurrent part: sum_j h[j] * Wh[j][u]
#pragma unroll
        for (int j = 0; j < U; j += 4) {
            const float4 h4 = *reinterpret_cast<const float4*>(&hbuf[cur][j]);
            a0 += h4.x * wcol[j + 0];
            a1 += h4.y * wcol[j + 1];
            a2 += h4.z * wcol[j + 2];
            a3 += h4.w * wcol[j + 3];
        }

        const float acc = (a0 + a1) + (a2 + a3);
        const float hn  = tanhf(acc);

        orow[(size_t)t * U + u] = hn;       // coalesced 1 KB store
        hbuf[nxt][u] = hn;                  // publish next h
        if (u < D && t + 1 < T) xb[nxt][u] = xn;
        __syncthreads();                    // single barrier per step
    }
}

extern "C" void kernel_launch(void* const* d_in, const int* in_sizes, int n_in,
                              void* d_out, int out_size, void* d_ws, size_t ws_size,
                              hipStream_t stream) {
    const float* x    = (const float*)d_in[0];
    const float* h0   = (const float*)d_in[1];
    const float* W    = (const float*)d_in[2];
    const float* bias = (const float*)d_in[3];
    float* out = (float*)d_out;

    dim3 grid(B);
    dim3 block(U);
    hipLaunchKernelGGL(rnn_fused_kernel, grid, block, 0, stream,
                       x, h0, W, bias, out);
}

// Round 2
// 1449.669 us; speedup vs baseline: 1.8549x; 1.8549x over previous
//
#include <hip/hip_runtime.h>

// MyRNNCell via MFMA f16 on gfx950.
//
//   Wh = W[0:256], Wx = W[256:384];  h_{t+1} = tanh([h_t | x_t] @ W + bias)
//
// 16 workgroups x 16 batches (MFMA M=16 is the batch-parallel quantum).
// 256 threads = 4 waves; wave w owns units [64w, 64w+64) = 4 N-tiles of 16.
// K = 384 = 12 slices of 32:  k 0..255 = h,  k 256..383 = x_t.
//
// Per step: read 12 A-frags from LDS (A[m=lane&15][k=(lane>>4)*8+j], m120-
// verified layout), 48 mfma_f32_16x16x32_f16 accumulating from C=bias,
// tanh epilogue (C-layout: n=lane&15, m=(lane>>4)*4+reg, m89-verified),
// store fp32 out, publish h_new as f16 back into the A-buffer for t+1
// (the C->A relayout LDS round-trip, as in flash-attention m120).
// x_{t+1} staged into A slots 256..383; double-buffered; ONE barrier/step.
// x prefetched 2 steps ahead (issue at t, LDS-publish at t+1) to cover
// ~900cyc HBM latency with ~2 step-times.
//
// fp16 (not bf16): 2^-11 quantization keeps recurrent error ~1e-3 << 2e-2.
// W fragments (B operand, B[k][n]: n=lane&15, k=(lane>>4)*8+j) live in
// registers: 4 tiles x 12 slices x 4 VGPR = 192 VGPRs; fits at 1 wave/SIMD.

typedef _Float16 half8 __attribute__((ext_vector_type(8)));
typedef float floatx4 __attribute__((ext_vector_type(4)));

constexpr int B = 256, T = 1024, D = 128, U = 256;
constexpr int NSL = (U + D) / 32;      // 12 K-slices
constexpr int QS  = 16 * 16 + 16;      // 272 B quad stride (+16 pad: bank spread)
constexpr int SS  = 4 * QS;            // 1088 B slice stride
constexpr int BUF = NSL * SS;          // 13056 B per A-buffer

__device__ __forceinline__ float fexp2(float v) {
#if __has_builtin(__builtin_amdgcn_exp2f)
    return __builtin_amdgcn_exp2f(v);
#else
    return exp2f(v);
#endif
}
__device__ __forceinline__ float frcp(float v) {
#if __has_builtin(__builtin_amdgcn_rcpf)
    return __builtin_amdgcn_rcpf(v);
#else
    return 1.0f / v;
#endif
}
// tanh(v) = 1 - 2/(e^{2v}+1).  exp2->inf and rcp(inf)=0 make saturation
// exact at both ends without clamping.
__device__ __forceinline__ float fast_tanh(float v) {
    float e = fexp2(2.8853900817779268f * v);   // e^{2v} = 2^{2v*log2(e)}
    return 1.0f - 2.0f * frcp(e + 1.0f);
}

__device__ __forceinline__ void cvt_write8(void* dst, float4 lo, float4 hi) {
    half8 h;
    h[0] = (_Float16)lo.x; h[1] = (_Float16)lo.y;
    h[2] = (_Float16)lo.z; h[3] = (_Float16)lo.w;
    h[4] = (_Float16)hi.x; h[5] = (_Float16)hi.y;
    h[6] = (_Float16)hi.z; h[7] = (_Float16)hi.w;
    *reinterpret_cast<half8*>(dst) = h;
}

__global__ __launch_bounds__(256, 1)
void rnn_mfma_kernel(const float* __restrict__ x, const float* __restrict__ h0,
                     const float* __restrict__ W, const float* __restrict__ bias,
                     float* __restrict__ out)
{
    __shared__ __align__(16) unsigned char lds[2 * BUF];

    const int tid  = threadIdx.x;
    const int lane = tid & 63;
    const int wv   = tid >> 6;     // wave 0..3, owns units [64wv, 64wv+64)
    const int l15  = lane & 15;
    const int quad = lane >> 4;
    const int b0   = blockIdx.x * 16;

    // ---- W fragments (B operand) + bias, one-time ----
    half8 wf[4][NSL];
    float bv[4];
#pragma unroll
    for (int nt = 0; nt < 4; ++nt) {
        const int n = 64 * wv + 16 * nt + l15;
        bv[nt] = bias[n];
#pragma unroll
        for (int s = 0; s < NSL; ++s) {
            half8 f;
#pragma unroll
            for (int j = 0; j < 8; ++j) {
                const int k = 32 * s + 8 * quad + j;
                f[j] = (_Float16)W[(size_t)k * U + n];
            }
            wf[nt][s] = f;
        }
    }

    // ---- stage h0 (slices 0..7) and x_0 (slices 8..11) into buffer 0 ----
    const int sm = tid >> 4;   // staging batch row 0..15
    const int sc = tid & 15;   // staging chunk
#pragma unroll
    for (int cc = sc; cc < 32; cc += 16) {           // h0: 32 chunks of 8 units
        const float* hp = h0 + (size_t)(b0 + sm) * U + 8 * cc;
        cvt_write8(lds + (cc >> 2) * SS + (cc & 3) * QS + sm * 16,
                   *reinterpret_cast<const float4*>(hp),
                   *reinterpret_cast<const float4*>(hp + 4));
    }
    const float* xbase = x + (size_t)(b0 + sm) * T * D + 8 * sc;
    cvt_write8(lds + (8 + (sc >> 2)) * SS + (sc & 3) * QS + sm * 16,
               *reinterpret_cast<const float4*>(xbase),
               *reinterpret_cast<const float4*>(xbase + 4));

    // prefetch x row 1 (published to LDS during step 0)
    float4 p0 = *reinterpret_cast<const float4*>(xbase + D);
    float4 p1 = *reinterpret_cast<const float4*>(xbase + D + 4);

    __syncthreads();

    for (int t = 0; t < T; ++t) {
        const int cur = t & 1, nxt = cur ^ 1;

        // issue prefetch for t+2 (consumed next step -> ~1 step of latency slack)
        const int tp = (t + 2 < T) ? (t + 2) : (T - 1);
        float4 q0 = *reinterpret_cast<const float4*>(xbase + (size_t)D * tp);
        float4 q1 = *reinterpret_cast<const float4*>(xbase + (size_t)D * tp + 4);

        // A fragments: [h_t | x_t]
        half8 a[NSL];
        const unsigned char* ab = lds + cur * BUF + quad * QS + l15 * 16;
#pragma unroll
        for (int s = 0; s < NSL; ++s)
            a[s] = *reinterpret_cast<const half8*>(ab + s * SS);

        floatx4 acc[4];
#pragma unroll
        for (int nt = 0; nt < 4; ++nt)
            acc[nt] = (floatx4){bv[nt], bv[nt], bv[nt], bv[nt]};
#pragma unroll
        for (int s = 0; s < NSL; ++s)
#pragma unroll
            for (int nt = 0; nt < 4; ++nt)
                acc[nt] = __builtin_amdgcn_mfma_f32_16x16x32_f16(
                              a[s], wf[nt][s], acc[nt], 0, 0, 0);

        // epilogue: tanh, fp32 store, f16 publish into LDS[nxt] A-layout
        unsigned char* hb = lds + nxt * BUF;
        float* orow = out + (size_t)t * U;
#pragma unroll
        for (int nt = 0; nt < 4; ++nt) {
            const int n = 64 * wv + 16 * nt + l15;
#pragma unroll
            for (int r = 0; r < 4; ++r) {
                const int m = 4 * quad + r;
                const float h = fast_tanh(acc[nt][r]);
                orow[(size_t)(b0 + m) * T * U + n] = h;
                *reinterpret_cast<_Float16*>(
                    hb + (n >> 5) * SS + ((n >> 3) & 3) * QS + m * 16 + (n & 7) * 2)
                    = (_Float16)h;
            }
        }

        // publish x_{t+1} (loaded last step) into LDS[nxt] slices 8..11
        cvt_write8(hb + (8 + (sc >> 2)) * SS + (sc & 3) * QS + sm * 16, p0, p1);
        p0 = q0; p1 = q1;

        __syncthreads();
    }
}

extern "C" void kernel_launch(void* const* d_in, const int* in_sizes, int n_in,
                              void* d_out, int out_size, void* d_ws, size_t ws_size,
                              hipStream_t stream) {
    const float* x    = (const float*)d_in[0];
    const float* h0   = (const float*)d_in[1];
    const float* W    = (const float*)d_in[2];
    const float* bias = (const float*)d_in[3];
    float* out = (float*)d_out;

    hipLaunchKernelGGL(rnn_mfma_kernel, dim3(B / 16), dim3(256), 0, stream,
                       x, h0, W, bias, out);
}